// Round 6
// baseline (7588.702 us; speedup 1.0000x reference)
//
#include <hip/hip_runtime.h>

// 2-layer LSTM (B=64, T=2048, H=256), persistent single-XCD kernel.
// R6: flip GEMM orientation. A = weights (M=32 gate rows), B = h (N=batch),
// using mfma_f32_32x32x16_bf16. C-layout (col=lane&31, row=(reg&3)+8*(reg>>2)
// +4*(lane>>5)) => lane (batch=col, hi) holds ALL 4 gates for dims 4hi..4hi+3
// => epilogue entirely in registers: no LDS gate transpose, no mid-phase
// __syncthreads, cell state / biases / Wih0(fp32) / Wfc in VGPRs.
// Wave jobs: wave0: L0 b0..31, wave1: L0 b32..63, wave2: L1 b0..31, wave3: L1 b32..63.
// Barrier/coherence machinery identical to R5 (elected XCD, write-through
// publishes, buffer_inv sc0 + plain L2 loads, atomic-or0 sc0 flag polls).

#define NWG 32
#define BB 64
#define TT 2048
#define HH 256
#define HS 8    // hidden dims per WG per layer
// workspace layout (dwords)
#define WS_H0    0        // 16384 dwords
#define WS_H1    16384    // 16384 dwords
#define WS_FLAGS 32768    // 32 flags, stride 16 dwords
#define WS_CNT   33280    // 16 dwords
#define WS_WIN   33296    // 1 dword
#define WS_NZERO 33296

typedef float  f32x16 __attribute__((ext_vector_type(16)));
typedef __bf16 bf16x8 __attribute__((ext_vector_type(8)));
typedef unsigned long long u64;
typedef unsigned int u32;

__device__ __forceinline__ float sigf(float x)   { return 1.0f / (1.0f + __expf(-x)); }
__device__ __forceinline__ float tanh_f(float x) { return 2.0f / (1.0f + __expf(-2.0f * x)) - 1.0f; }

// Atomic-or-0 with return, forced at the local TCC (L2). sc0 = return old.
__device__ __forceinline__ int poll_or0_sc0(int* p) {
  int old;
  asm volatile("global_atomic_or %0, %1, %2, off sc0\n\t"
               "s_waitcnt vmcnt(0)"
               : "=&v"(old)
               : "v"(p), "v"(0)
               : "memory");
  return old;
}

__global__ void init_ws(u32* ws) {
  int i = blockIdx.x * blockDim.x + threadIdx.x;
  for (; i < WS_NZERO; i += gridDim.x * blockDim.x) ws[i] = 0u;
  if (blockIdx.x == 0 && threadIdx.x == 0) ((int*)ws)[WS_WIN] = -1;
}

__global__ __launch_bounds__(256, 1) void lstm2_persistent(
    const float* __restrict__ y,
    const float* __restrict__ Wih0, const float* __restrict__ Whh0,
    const float* __restrict__ bih0, const float* __restrict__ bhh0,
    const float* __restrict__ Wih1, const float* __restrict__ Whh1,
    const float* __restrict__ bih1, const float* __restrict__ bhh1,
    const float* __restrict__ Wfc,  const float* __restrict__ bfc,
    float* __restrict__ out,
    u32* __restrict__ ws)
{
  __bf16* h0buf = (__bf16*)(ws + WS_H0);   // [2][NWG][BB][HS]
  __bf16* h1buf = (__bf16*)(ws + WS_H1);   // [2][NWG][BB][HS]
  int*    flags = (int*)(ws + WS_FLAGS);
  int*    cnt   = (int*)(ws + WS_CNT);
  int*    winner= (int*)(ws + WS_WIN);

  const int tid = threadIdx.x;

  // ---- same-XCD election (as R5) ----
  __shared__ int s_w;
  if (tid == 0) {
    int xcc = __builtin_amdgcn_s_getreg(20 | (31 << 11)) & 0xF;
    int r = atomicAdd(&cnt[xcc], 1);
    if (r == NWG - 1) atomicCAS(winner, -1, xcc);
    int wv;
    while ((wv = __hip_atomic_load(winner, __ATOMIC_RELAXED,
                                   __HIP_MEMORY_SCOPE_AGENT)) == -1) {}
    s_w = (wv == xcc && r < NWG) ? r : -1;
  }
  __syncthreads();
  const int w = s_w;
  if (w < 0) return;

  const int wid  = tid >> 6;     // wave job id
  const int lane = tid & 63;
  const int r32  = lane & 31;    // A row / B col
  const int hi   = lane >> 5;    // k-half select, and dim-half in C
  const bool isL0 = (wid < 2);
  const int bN   = (wid & 1) * 32 + r32;   // batch owned by this lane

  // ---- preload weights into registers ----
  bf16x8 aW[32];        // L0 waves use [0..15] (Whh0); L1 waves all 32 ([Wih1|Whh1])
  float  wx[16][4];     // L0 only: Wih0 rows (fp32, keeps -100-padding precision)
  float  bias[16];
  float  wfcv[8]; float bfcv = 0.f; int fcb = 0;
  {
    const int gate  = r32 >> 3, dloc = r32 & 7;
    const int rglob = gate * 256 + w * HS + dloc;   // A-row r32 = 8*gate + dloc
    if (isL0) {
      #pragma unroll
      for (int s = 0; s < 16; s++) {
        const float* src = Whh0 + rglob * HH + s * 16 + hi * 8;
        bf16x8 f;
        #pragma unroll
        for (int j = 0; j < 8; j++) f[j] = (__bf16)src[j];
        aW[s] = f;
      }
    } else {
      #pragma unroll
      for (int s = 0; s < 16; s++) {
        const float* src = Wih1 + rglob * HH + s * 16 + hi * 8;
        bf16x8 f;
        #pragma unroll
        for (int j = 0; j < 8; j++) f[j] = (__bf16)src[j];
        aW[s] = f;
      }
      #pragma unroll
      for (int s = 0; s < 16; s++) {
        const float* src = Whh1 + rglob * HH + s * 16 + hi * 8;
        bf16x8 f;
        #pragma unroll
        for (int j = 0; j < 8; j++) f[j] = (__bf16)src[j];
        aW[16 + s] = f;
      }
    }
    // per-C-reg tables: reg q -> row (q&3)+8*(q>>2)+4*hi = gate (q>>2), dim 4hi+(q&3)
    #pragma unroll
    for (int q = 0; q < 16; q++) {
      const int row = (q & 3) + 8 * (q >> 2) + 4 * hi;
      const int rg  = (row >> 3) * 256 + w * HS + (row & 7);
      bias[q] = isL0 ? (bih0[rg] + bhh0[rg]) : (bih1[rg] + bhh1[rg]);
      if (isL0) {
        #pragma unroll
        for (int j = 0; j < 4; j++) wx[q][j] = Wih0[rg * 4 + j];
      }
    }
    if (wid == 1 || wid == 2) {       // FC duty: wave1 -> batch 2w, wave2 -> 2w+1
      fcb = 2 * w + (wid - 1);
      #pragma unroll
      for (int j = 0; j < 8; j++) wfcv[j] = Wfc[hi * HH + r32 * 8 + j];
      bfcv = bfc[hi];
    }
  }

  float cst[4] = {0.f, 0.f, 0.f, 0.f};          // cell state (4 dims)
  float x1 = -100.f, x2 = -100.f, x3 = -100.f;  // y window tail (x0 shifts in)

  for (int p = 0; p < TT + 2; p++) {
    const int par  = p & 1;
    const int parm = par ^ 1;
    const bool doL0 = (p < TT);
    const bool doL1 = (p >= 1 && p <= TT);

    asm volatile("buffer_inv sc0" ::: "memory");   // drop stale L1, read fresh L2

    // ---- issue all loads up front ----
    bf16x8 bh0[16], bh1[16];
    float ycur = -100.f;
    bf16x8 hfc = {};
    if (isL0) {
      const __bf16* hp = h0buf + ((u32)(parm * NWG) * BB + bN) * HS;
      #pragma unroll
      for (int s = 0; s < 16; s++)
        bh0[s] = *(const bf16x8*)(hp + (s * 2 + hi) * BB * HS);
      if (doL0) ycur = y[bN * TT + p];
    } else {
      const __bf16* hp0 = h0buf + ((u32)(parm * NWG) * BB + bN) * HS;
      const __bf16* hp1 = h1buf + ((u32)(par  * NWG) * BB + bN) * HS;
      #pragma unroll
      for (int s = 0; s < 16; s++)
        bh0[s] = *(const bf16x8*)(hp0 + (s * 2 + hi) * BB * HS);
      #pragma unroll
      for (int s = 0; s < 16; s++)
        bh1[s] = *(const bf16x8*)(hp1 + (s * 2 + hi) * BB * HS);
    }
    if ((wid == 1 || wid == 2) && p >= 2)
      hfc = *(const bf16x8*)(h1buf + (((u32)par * NWG + r32) * BB + fcb) * HS);

    // ---- MFMA: acc[q] = gates, A=weights B=h ----
    f32x16 acc;
    #pragma unroll
    for (int q = 0; q < 16; q++) acc[q] = 0.f;
    if (isL0) {
      if (doL0) {
        #pragma unroll
        for (int s = 0; s < 16; s++)
          acc = __builtin_amdgcn_mfma_f32_32x32x16_bf16(aW[s], bh0[s], acc, 0, 0, 0);
      }
    } else {
      if (doL1) {
        #pragma unroll
        for (int s = 0; s < 16; s++)
          acc = __builtin_amdgcn_mfma_f32_32x32x16_bf16(aW[s], bh0[s], acc, 0, 0, 0);
        #pragma unroll
        for (int s = 0; s < 16; s++)
          acc = __builtin_amdgcn_mfma_f32_32x32x16_bf16(aW[16 + s], bh1[s], acc, 0, 0, 0);
      }
    }

    // ---- in-register epilogue + publish ----
    if (isL0 && doL0) {
      const float x0 = x1; x1 = x2; x2 = x3; x3 = ycur;   // window = y[p-3..p]
      union { __bf16 h[4]; u64 u; } pk;
      #pragma unroll
      for (int dd = 0; dd < 4; dd++) {
        const float gi = acc[dd]      + bias[dd]
          + wx[dd][0]*x0 + wx[dd][1]*x1 + wx[dd][2]*x2 + wx[dd][3]*x3;
        const float gf = acc[4 + dd]  + bias[4 + dd]
          + wx[4+dd][0]*x0 + wx[4+dd][1]*x1 + wx[4+dd][2]*x2 + wx[4+dd][3]*x3;
        const float gg = acc[8 + dd]  + bias[8 + dd]
          + wx[8+dd][0]*x0 + wx[8+dd][1]*x1 + wx[8+dd][2]*x2 + wx[8+dd][3]*x3;
        const float go = acc[12 + dd] + bias[12 + dd]
          + wx[12+dd][0]*x0 + wx[12+dd][1]*x1 + wx[12+dd][2]*x2 + wx[12+dd][3]*x3;
        const float cn = sigf(gf) * cst[dd] + sigf(gi) * tanh_f(gg);
        cst[dd] = cn;
        pk.h[dd] = (__bf16)(sigf(go) * tanh_f(cn));
      }
      *(u64*)(h0buf + (((u32)par * NWG + w) * BB + bN) * HS + 4 * hi) = pk.u;
    }
    if (!isL0 && doL1) {
      union { __bf16 h[4]; u64 u; } pk;
      #pragma unroll
      for (int dd = 0; dd < 4; dd++) {
        const float gi = acc[dd]      + bias[dd];
        const float gf = acc[4 + dd]  + bias[4 + dd];
        const float gg = acc[8 + dd]  + bias[8 + dd];
        const float go = acc[12 + dd] + bias[12 + dd];
        const float cn = sigf(gf) * cst[dd] + sigf(gi) * tanh_f(gg);
        cst[dd] = cn;
        pk.h[dd] = (__bf16)(sigf(go) * tanh_f(cn));
      }
      *(u64*)(h1buf + (((u32)parm * NWG + w) * BB + bN) * HS + 4 * hi) = pk.u;
    }

    // ---- drain publishes to L2, stamp flag ----
    asm volatile("s_waitcnt vmcnt(0)" ::: "memory");
    __syncthreads();
    if (tid == 0)
      __hip_atomic_store(&flags[w * 16], p + 2, __ATOMIC_RELAXED,
                         __HIP_MEMORY_SCOPE_WORKGROUP);

    // ---- FC for step p-2 (overlaps flag propagation; waves 1,2) ----
    if ((wid == 1 || wid == 2) && p >= 2) {
      float s = 0.f;
      #pragma unroll
      for (int j = 0; j < 8; j++) s += (float)hfc[j] * wfcv[j];
      s += __shfl_down(s, 16, 64);
      s += __shfl_down(s, 8, 64);
      s += __shfl_down(s, 4, 64);
      s += __shfl_down(s, 2, 64);
      s += __shfl_down(s, 1, 64);
      if (r32 == 0) out[fcb * (TT * 2) + (p - 2) * 2 + hi] = s + bfcv;
    }

    // ---- barrier wait (wave0 lanes poll local-TCC atomics) ----
    if (tid < NWG) {
      while (poll_or0_sc0(&flags[tid * 16]) < p + 2) {}
    }
    __syncthreads();
  }
}

extern "C" void kernel_launch(void* const* d_in, const int* in_sizes, int n_in,
                              void* d_out, int out_size, void* d_ws, size_t ws_size,
                              hipStream_t stream) {
  u32* ws = (u32*)d_ws;
  init_ws<<<dim3(64), dim3(256), 0, stream>>>(ws);
  lstm2_persistent<<<dim3(256), dim3(256), 0, stream>>>(
      (const float*)d_in[0],  (const float*)d_in[1], (const float*)d_in[2],
      (const float*)d_in[3],  (const float*)d_in[4], (const float*)d_in[5],
      (const float*)d_in[6],  (const float*)d_in[7], (const float*)d_in[8],
      (const float*)d_in[9],  (const float*)d_in[10],
      (float*)d_out, ws);
}

// Round 7
// 7383.050 us; speedup vs baseline: 1.0279x; 1.0279x over previous
//
#include <hip/hip_runtime.h>

// 2-layer LSTM (B=64, T=2048, H=256), persistent single-XCD kernel.
// R7 = R6 + two changes:
//  (1) CLOCK KEEPERS: the 224 non-participant WGs no longer exit (leaving the
//      chip 99% idle -> DPM parks sclk at ~650MHz, matching the consistent
//      ~3.5x gap between cycle models and measured time, and the 6.4x outlier
//      dispatches). They burn independent VALU FMAs, checking a done-flag
//      (agent scope, IC) every ~4K ops, exiting when participants finish.
//  (2) MFMA dependent chains split in two (L1: 2x16, L0: 2x8) + vector add,
//      removing ~300-500cyc of serial result-forwarding latency per phase.
// Everything else as R6: A=weights/B=h mfma_32x32x16 with in-register epilogue,
// elected single-XCD WG set, write-through h publishes, buffer_inv sc0 + plain
// L2 loads, atomic-or0 sc0 flag polls.

#define NWG 32
#define BB 64
#define TT 2048
#define HH 256
#define HS 8    // hidden dims per WG per layer
// workspace layout (dwords)
#define WS_H0    0        // 16384 dwords
#define WS_H1    16384    // 16384 dwords
#define WS_FLAGS 32768    // 32 flags, stride 16 dwords
#define WS_CNT   33280    // 16 dwords
#define WS_WIN   33296    // 1 dword (set to -1 by init)
#define WS_DONE  33297    // 1 dword (0 = running)
#define WS_NZERO 33296    // zeroed [0, WS_NZERO)

typedef float  f32x16 __attribute__((ext_vector_type(16)));
typedef __bf16 bf16x8 __attribute__((ext_vector_type(8)));
typedef unsigned long long u64;
typedef unsigned int u32;

__device__ __forceinline__ float sigf(float x)   { return 1.0f / (1.0f + __expf(-x)); }
__device__ __forceinline__ float tanh_f(float x) { return 2.0f / (1.0f + __expf(-2.0f * x)) - 1.0f; }

// Atomic-or-0 with return, forced at the local TCC (L2). sc0 = return old.
__device__ __forceinline__ int poll_or0_sc0(int* p) {
  int old;
  asm volatile("global_atomic_or %0, %1, %2, off sc0\n\t"
               "s_waitcnt vmcnt(0)"
               : "=&v"(old)
               : "v"(p), "v"(0)
               : "memory");
  return old;
}

__global__ void init_ws(u32* ws) {
  int i = blockIdx.x * blockDim.x + threadIdx.x;
  for (; i < WS_NZERO; i += gridDim.x * blockDim.x) ws[i] = 0u;
  if (blockIdx.x == 0 && threadIdx.x == 0) {
    ((int*)ws)[WS_WIN]  = -1;
    ((int*)ws)[WS_DONE] = 0;
  }
}

__global__ __launch_bounds__(256, 1) void lstm2_persistent(
    const float* __restrict__ y,
    const float* __restrict__ Wih0, const float* __restrict__ Whh0,
    const float* __restrict__ bih0, const float* __restrict__ bhh0,
    const float* __restrict__ Wih1, const float* __restrict__ Whh1,
    const float* __restrict__ bih1, const float* __restrict__ bhh1,
    const float* __restrict__ Wfc,  const float* __restrict__ bfc,
    float* __restrict__ out,
    u32* __restrict__ ws)
{
  __bf16* h0buf = (__bf16*)(ws + WS_H0);   // [2][NWG][BB][HS]
  __bf16* h1buf = (__bf16*)(ws + WS_H1);   // [2][NWG][BB][HS]
  int*    flags = (int*)(ws + WS_FLAGS);
  int*    cnt   = (int*)(ws + WS_CNT);
  int*    winner= (int*)(ws + WS_WIN);
  int*    done  = (int*)(ws + WS_DONE);

  const int tid = threadIdx.x;

  // ---- same-XCD election ----
  __shared__ int s_w;
  if (tid == 0) {
    int xcc = __builtin_amdgcn_s_getreg(20 | (31 << 11)) & 0xF;
    int r = atomicAdd(&cnt[xcc], 1);
    if (r == NWG - 1) atomicCAS(winner, -1, xcc);
    int wv;
    while ((wv = __hip_atomic_load(winner, __ATOMIC_RELAXED,
                                   __HIP_MEMORY_SCOPE_AGENT)) == -1) {}
    s_w = (wv == xcc && r < NWG) ? r : -1;
  }
  __syncthreads();
  const int w = s_w;

  if (w < 0) {
    // ---- clock keeper: high-duty VALU burn until participants finish ----
    float a0 = (float)tid * 0.5f + 1.0f;
    float a1 = a0 + 0.25f, a2 = a0 + 0.5f, a3 = a0 + 0.75f;
    for (;;) {
      #pragma unroll 32
      for (int i = 0; i < 1024; i++) {
        a0 = __builtin_fmaf(a0, 0.9999999f, 1e-7f);
        a1 = __builtin_fmaf(a1, 0.9999999f, 1e-7f);
        a2 = __builtin_fmaf(a2, 0.9999999f, 1e-7f);
        a3 = __builtin_fmaf(a3, 0.9999999f, 1e-7f);
      }
      asm volatile("" : "+v"(a0), "+v"(a1), "+v"(a2), "+v"(a3));
      if (__hip_atomic_load(done, __ATOMIC_RELAXED,
                            __HIP_MEMORY_SCOPE_AGENT) != 0) break;
    }
    return;
  }

  const int wid  = tid >> 6;     // wave job id
  const int lane = tid & 63;
  const int r32  = lane & 31;    // A row / B col
  const int hi   = lane >> 5;    // k-half select, and dim-half in C
  const bool isL0 = (wid < 2);
  const int bN   = (wid & 1) * 32 + r32;   // batch owned by this lane

  // ---- preload weights into registers ----
  bf16x8 aW[32];        // L0 waves use [0..15] (Whh0); L1 waves all 32 ([Wih1|Whh1])
  float  wx[16][4];     // L0 only: Wih0 rows (fp32)
  float  bias[16];
  float  wfcv[8]; float bfcv = 0.f; int fcb = 0;
  {
    const int gate  = r32 >> 3, dloc = r32 & 7;
    const int rglob = gate * 256 + w * HS + dloc;   // A-row r32 = 8*gate + dloc
    if (isL0) {
      #pragma unroll
      for (int s = 0; s < 16; s++) {
        const float* src = Whh0 + rglob * HH + s * 16 + hi * 8;
        bf16x8 f;
        #pragma unroll
        for (int j = 0; j < 8; j++) f[j] = (__bf16)src[j];
        aW[s] = f;
      }
    } else {
      #pragma unroll
      for (int s = 0; s < 16; s++) {
        const float* src = Wih1 + rglob * HH + s * 16 + hi * 8;
        bf16x8 f;
        #pragma unroll
        for (int j = 0; j < 8; j++) f[j] = (__bf16)src[j];
        aW[s] = f;
      }
      #pragma unroll
      for (int s = 0; s < 16; s++) {
        const float* src = Whh1 + rglob * HH + s * 16 + hi * 8;
        bf16x8 f;
        #pragma unroll
        for (int j = 0; j < 8; j++) f[j] = (__bf16)src[j];
        aW[16 + s] = f;
      }
    }
    // per-C-reg tables: reg q -> row (q&3)+8*(q>>2)+4*hi => gate q>>2, dim 4hi+(q&3)
    #pragma unroll
    for (int q = 0; q < 16; q++) {
      const int row = (q & 3) + 8 * (q >> 2) + 4 * hi;
      const int rg  = (row >> 3) * 256 + w * HS + (row & 7);
      bias[q] = isL0 ? (bih0[rg] + bhh0[rg]) : (bih1[rg] + bhh1[rg]);
      if (isL0) {
        #pragma unroll
        for (int j = 0; j < 4; j++) wx[q][j] = Wih0[rg * 4 + j];
      }
    }
    if (wid == 1 || wid == 2) {       // FC duty: wave1 -> batch 2w, wave2 -> 2w+1
      fcb = 2 * w + (wid - 1);
      #pragma unroll
      for (int j = 0; j < 8; j++) wfcv[j] = Wfc[hi * HH + r32 * 8 + j];
      bfcv = bfc[hi];
    }
  }

  float cst[4] = {0.f, 0.f, 0.f, 0.f};          // cell state (4 dims)
  float x1 = -100.f, x2 = -100.f, x3 = -100.f;  // y window tail

  for (int p = 0; p < TT + 2; p++) {
    const int par  = p & 1;
    const int parm = par ^ 1;
    const bool doL0 = (p < TT);
    const bool doL1 = (p >= 1 && p <= TT);

    asm volatile("buffer_inv sc0" ::: "memory");   // drop stale L1, read fresh L2

    // ---- issue all loads up front ----
    bf16x8 bh0[16], bh1[16];
    float ycur = -100.f;
    bf16x8 hfc = {};
    if (isL0) {
      const __bf16* hp = h0buf + ((u32)(parm * NWG) * BB + bN) * HS;
      #pragma unroll
      for (int s = 0; s < 16; s++)
        bh0[s] = *(const bf16x8*)(hp + (s * 2 + hi) * BB * HS);
      if (doL0) ycur = y[bN * TT + p];
    } else {
      const __bf16* hp0 = h0buf + ((u32)(parm * NWG) * BB + bN) * HS;
      const __bf16* hp1 = h1buf + ((u32)(par  * NWG) * BB + bN) * HS;
      #pragma unroll
      for (int s = 0; s < 16; s++)
        bh0[s] = *(const bf16x8*)(hp0 + (s * 2 + hi) * BB * HS);
      #pragma unroll
      for (int s = 0; s < 16; s++)
        bh1[s] = *(const bf16x8*)(hp1 + (s * 2 + hi) * BB * HS);
    }
    if ((wid == 1 || wid == 2) && p >= 2)
      hfc = *(const bf16x8*)(h1buf + (((u32)par * NWG + r32) * BB + fcb) * HS);

    // ---- MFMA: two independent dep chains, merged with a vector add ----
    f32x16 acc, acc2;
    #pragma unroll
    for (int q = 0; q < 16; q++) { acc[q] = 0.f; acc2[q] = 0.f; }
    if (isL0) {
      if (doL0) {
        #pragma unroll
        for (int s = 0; s < 8; s++)
          acc  = __builtin_amdgcn_mfma_f32_32x32x16_bf16(aW[s],     bh0[s],     acc,  0, 0, 0);
        #pragma unroll
        for (int s = 0; s < 8; s++)
          acc2 = __builtin_amdgcn_mfma_f32_32x32x16_bf16(aW[8 + s], bh0[8 + s], acc2, 0, 0, 0);
        acc = acc + acc2;
      }
    } else {
      if (doL1) {
        #pragma unroll
        for (int s = 0; s < 16; s++)
          acc  = __builtin_amdgcn_mfma_f32_32x32x16_bf16(aW[s],      bh0[s], acc,  0, 0, 0);
        #pragma unroll
        for (int s = 0; s < 16; s++)
          acc2 = __builtin_amdgcn_mfma_f32_32x32x16_bf16(aW[16 + s], bh1[s], acc2, 0, 0, 0);
        acc = acc + acc2;
      }
    }

    // ---- in-register epilogue + publish ----
    if (isL0 && doL0) {
      const float x0 = x1; x1 = x2; x2 = x3; x3 = ycur;   // window = y[p-3..p]
      union { __bf16 h[4]; u64 u; } pk;
      #pragma unroll
      for (int dd = 0; dd < 4; dd++) {
        const float gi = acc[dd]      + bias[dd]
          + wx[dd][0]*x0 + wx[dd][1]*x1 + wx[dd][2]*x2 + wx[dd][3]*x3;
        const float gf = acc[4 + dd]  + bias[4 + dd]
          + wx[4+dd][0]*x0 + wx[4+dd][1]*x1 + wx[4+dd][2]*x2 + wx[4+dd][3]*x3;
        const float gg = acc[8 + dd]  + bias[8 + dd]
          + wx[8+dd][0]*x0 + wx[8+dd][1]*x1 + wx[8+dd][2]*x2 + wx[8+dd][3]*x3;
        const float go = acc[12 + dd] + bias[12 + dd]
          + wx[12+dd][0]*x0 + wx[12+dd][1]*x1 + wx[12+dd][2]*x2 + wx[12+dd][3]*x3;
        const float cn = sigf(gf) * cst[dd] + sigf(gi) * tanh_f(gg);
        cst[dd] = cn;
        pk.h[dd] = (__bf16)(sigf(go) * tanh_f(cn));
      }
      *(u64*)(h0buf + (((u32)par * NWG + w) * BB + bN) * HS + 4 * hi) = pk.u;
    }
    if (!isL0 && doL1) {
      union { __bf16 h[4]; u64 u; } pk;
      #pragma unroll
      for (int dd = 0; dd < 4; dd++) {
        const float gi = acc[dd]      + bias[dd];
        const float gf = acc[4 + dd]  + bias[4 + dd];
        const float gg = acc[8 + dd]  + bias[8 + dd];
        const float go = acc[12 + dd] + bias[12 + dd];
        const float cn = sigf(gf) * cst[dd] + sigf(gi) * tanh_f(gg);
        cst[dd] = cn;
        pk.h[dd] = (__bf16)(sigf(go) * tanh_f(cn));
      }
      *(u64*)(h1buf + (((u32)parm * NWG + w) * BB + bN) * HS + 4 * hi) = pk.u;
    }

    // ---- drain publishes to L2, stamp flag ----
    asm volatile("s_waitcnt vmcnt(0)" ::: "memory");
    __syncthreads();
    if (tid == 0)
      __hip_atomic_store(&flags[w * 16], p + 2, __ATOMIC_RELAXED,
                         __HIP_MEMORY_SCOPE_WORKGROUP);

    // ---- FC for step p-2 (overlaps flag propagation; waves 1,2) ----
    if ((wid == 1 || wid == 2) && p >= 2) {
      float s = 0.f;
      #pragma unroll
      for (int j = 0; j < 8; j++) s += (float)hfc[j] * wfcv[j];
      s += __shfl_down(s, 16, 64);
      s += __shfl_down(s, 8, 64);
      s += __shfl_down(s, 4, 64);
      s += __shfl_down(s, 2, 64);
      s += __shfl_down(s, 1, 64);
      if (r32 == 0) out[fcb * (TT * 2) + (p - 2) * 2 + hi] = s + bfcv;
    }

    // ---- barrier wait (wave0 lanes poll local-TCC atomics) ----
    if (tid < NWG) {
      while (poll_or0_sc0(&flags[tid * 16]) < p + 2) {}
    }
    __syncthreads();
  }

  // ---- release the clock keepers ----
  if (w == 0 && tid == 0)
    __hip_atomic_store(done, 1, __ATOMIC_RELAXED, __HIP_MEMORY_SCOPE_AGENT);
}

extern "C" void kernel_launch(void* const* d_in, const int* in_sizes, int n_in,
                              void* d_out, int out_size, void* d_ws, size_t ws_size,
                              hipStream_t stream) {
  u32* ws = (u32*)d_ws;
  init_ws<<<dim3(64), dim3(256), 0, stream>>>(ws);
  lstm2_persistent<<<dim3(256), dim3(256), 0, stream>>>(
      (const float*)d_in[0],  (const float*)d_in[1], (const float*)d_in[2],
      (const float*)d_in[3],  (const float*)d_in[4], (const float*)d_in[5],
      (const float*)d_in[6],  (const float*)d_in[7], (const float*)d_in[8],
      (const float*)d_in[9],  (const float*)d_in[10],
      (float*)d_out, ws);
}